// Round 12
// baseline (168.151 us; speedup 1.0000x reference)
//
#include <hip/hip_runtime.h>

#define N_NODES 100000
#define N_EDGES 1600000
#define NB 782    // ceil(N_NODES/128) buckets of 128 dst-nodes
#define CAP 3072  // strip capacity per bucket (mean 2046, sigma 45 -> 22-sigma safe)
#define EPB 8192  // edges per pass1 block
#define NP1 196   // ceil(N_EDGES/EPB)
#define CVB 200   // convert blocks in prep
#define YP 72     // padded LDS row (bf16) for weights
#define AP 72     // padded LDS agg row (bf16)

typedef __attribute__((ext_vector_type(8))) short bhalf8;
typedef __attribute__((ext_vector_type(4))) float f32x4;

__device__ __forceinline__ unsigned short bf16r(float f) {
    unsigned u = __float_as_uint(f);
    unsigned r = (u >> 16) & 1;
    return (unsigned short)((u + 0x7fffu + r) >> 16);
}
__device__ __forceinline__ unsigned pk2(float a, float b) {
    return (unsigned)bf16r(a) | ((unsigned)bf16r(b) << 16);
}
__device__ __forceinline__ float bl(unsigned u) { return __uint_as_float(u << 16); }
__device__ __forceinline__ float bh(unsigned u) { return __uint_as_float(u & 0xffff0000u); }

// ---------------- prep: pass1 sort (blocks 0..NP1-1) || convert (rest) ---------
// pass1 reads src/dst ONCE (register-cached 16 edges/thread), then:
// hist -> scan -> strip reservation -> LDS rank -> linear coalesced flush.
__global__ __launch_bounds__(512) void prep(const float4* __restrict__ X4,
                                            uint2* __restrict__ Xb,
                                            const int* __restrict__ src,
                                            const int* __restrict__ dst,
                                            int* __restrict__ gcur,
                                            unsigned* __restrict__ ebuf) {
    __shared__ int h[NB];                // hist, then gdelta
    __shared__ int lo[NB];
    __shared__ int cur[NB];
    __shared__ int wsum[8];
    __shared__ unsigned stage[EPB];      // 32 KB
    __shared__ unsigned short bid[EPB];  // 16 KB
    int t = threadIdx.x, lane = t & 63, wid = t >> 6;
    if (blockIdx.x >= NP1) {  // convert branch
        for (int i = (blockIdx.x - NP1) * 512 + t; i < N_NODES * 16; i += CVB * 512) {
            float4 v = X4[i];
            uint2 o; o.x = pk2(v.x, v.y); o.y = pk2(v.z, v.w);
            Xb[i] = o;
        }
        return;
    }
    int e0 = blockIdx.x * EPB;
    int eN = N_EDGES - e0; if (eN > EPB) eN = EPB;
    for (int b = t; b < NB; b += 512) h[b] = 0;
    __syncthreads();
    unsigned pk[16]; unsigned short bk[16]; int ek = 0;
    for (int i = t; i < eN; i += 512) {
        int sd = src[e0 + i], dd = dst[e0 + i];
        int b = dd >> 7;
        pk[ek] = ((unsigned)sd << 7) | (unsigned)(dd & 127);
        bk[ek] = (unsigned short)b;
        ek++;
        atomicAdd(&h[b], 1);
    }
    __syncthreads();
    int i0 = 2 * t, i1 = i0 + 1;
    int v0 = (i0 < NB) ? h[i0] : 0;
    int v1 = (i1 < NB) ? h[i1] : 0;
    int ps = v0 + v1, s = ps;
    for (int o = 1; o < 64; o <<= 1) {
        int u = __shfl_up(s, o);
        if (lane >= o) s += u;
    }
    if (lane == 63) wsum[wid] = s;
    __syncthreads();
    int wofs = 0;
    for (int w = 0; w < wid; w++) wofs += wsum[w];
    int excl = wofs + s - ps;
    if (i0 < NB) lo[i0] = excl;
    if (i1 < NB) lo[i1] = excl + v0;
    __syncthreads();
    for (int b = t; b < NB; b += 512) {
        int hb = h[b];
        int ofs = hb ? atomicAdd(&gcur[b], hb) : 0;
        h[b] = b * CAP + ofs - lo[b];
        cur[b] = lo[b];
    }
    __syncthreads();
    for (int k = 0; k < ek; k++) {
        int b = bk[k];
        int r = atomicAdd(&cur[b], 1);
        stage[r] = pk[k];
        bid[r] = (unsigned short)b;
    }
    __syncthreads();
    for (int i = t; i < eN; i += 512)
        ebuf[h[bid[i]] + i] = stage[i];
}

// ---------------- bucket1: rank-sort + group-per-node gather + MFMA gemm -------
__global__ __launch_bounds__(512) void bucket1(
    const unsigned* __restrict__ ebuf, const int* __restrict__ gcur,
    const uint4* __restrict__ Xb4,
    const float* __restrict__ W1, const float* __restrict__ b1,
    const float* __restrict__ W2,
    unsigned short* __restrict__ Zb) {
    __shared__ int hh[128], nodeoff[129], scv[128];
    __shared__ unsigned short sW1t[64 * YP];   // 9216 B  W1^T [h][k]
    __shared__ unsigned short sW2t[32 * YP];   // 4608 B  W2^T [oc][h]
    __shared__ unsigned short agg[128 * AP];   // 18432 B agg tile [nl][ch] (bf16)
    __shared__ int stg[CAP];                   // 12288 B ranked src list

    int b = blockIdx.x, t = threadIdx.x;
    int base = b * CAP, cnt = gcur[b];
    int lane = t & 63, wid = t >> 6;
    if (t < 128) hh[t] = 0;
    for (int i = t; i < 64 * 64; i += 512) {
        int k = i >> 6, hc = i & 63;
        sW1t[hc * YP + k] = bf16r(W1[k * 64 + hc]);
    }
    for (int i = t; i < 64 * 32; i += 512) {
        int k = i >> 5, oc = i & 31;
        sW2t[oc * YP + k] = bf16r(W2[k * 32 + oc]);
    }
    __syncthreads();
    unsigned ev[6]; int ek = 0;
    for (int i = t; i < cnt; i += 512) {
        unsigned v = ebuf[base + i];
        ev[ek++] = v;
        atomicAdd(&hh[v & 127], 1);
    }
    __syncthreads();
    if (wid == 0) {  // wave-parallel exclusive scan of 128 (2 elems/lane)
        int v0 = hh[2 * lane], v1 = hh[2 * lane + 1];
        int ps = v0 + v1, s = ps;
        for (int o = 1; o < 64; o <<= 1) {
            int u = __shfl_up(s, o);
            if (lane >= o) s += u;
        }
        int excl = s - ps;
        nodeoff[2 * lane] = excl;
        nodeoff[2 * lane + 1] = excl + v0;
    }
    __syncthreads();
    if (t < 128) scv[t] = nodeoff[t];
    __syncthreads();
    for (int k = 0; k < ek; k++) {
        unsigned v = ev[k];
        int r = atomicAdd(&scv[v & 127], 1);
        stg[r] = (int)(v >> 7);
    }
    __syncthreads();

    // ---- gather: 8-lane group owns one node (8 ch/lane), 4 rows in flight ----
    int il = lane & 7, g = lane >> 3;
#pragma unroll
    for (int half = 0; half < 2; half++) {
        int nl = wid * 16 + half * 8 + g;
        int s0 = nodeoff[nl], d = hh[nl];
        float a0 = 0.f, a1 = 0.f, a2 = 0.f, a3 = 0.f;
        float a4 = 0.f, a5 = 0.f, a6 = 0.f, a7 = 0.f;
        int j = 0;
        for (; j + 3 < d; j += 4) {
            int sa = stg[s0 + j], sb = stg[s0 + j + 1];
            int sc = stg[s0 + j + 2], sd = stg[s0 + j + 3];
            uint4 va = Xb4[sa * 8 + il], vb = Xb4[sb * 8 + il];
            uint4 vc = Xb4[sc * 8 + il], vd = Xb4[sd * 8 + il];
            a0 += bl(va.x) + bl(vb.x) + bl(vc.x) + bl(vd.x);
            a1 += bh(va.x) + bh(vb.x) + bh(vc.x) + bh(vd.x);
            a2 += bl(va.y) + bl(vb.y) + bl(vc.y) + bl(vd.y);
            a3 += bh(va.y) + bh(vb.y) + bh(vc.y) + bh(vd.y);
            a4 += bl(va.z) + bl(vb.z) + bl(vc.z) + bl(vd.z);
            a5 += bh(va.z) + bh(vb.z) + bh(vc.z) + bh(vd.z);
            a6 += bl(va.w) + bl(vb.w) + bl(vc.w) + bl(vd.w);
            a7 += bh(va.w) + bh(vb.w) + bh(vc.w) + bh(vd.w);
        }
        for (; j < d; j++) {
            int sa = stg[s0 + j];
            uint4 va = Xb4[sa * 8 + il];
            a0 += bl(va.x); a1 += bh(va.x); a2 += bl(va.y); a3 += bh(va.y);
            a4 += bl(va.z); a5 += bh(va.z); a6 += bl(va.w); a7 += bh(va.w);
        }
        uint4 o;
        o.x = pk2(a0, a1); o.y = pk2(a2, a3);
        o.z = pk2(a4, a5); o.w = pk2(a6, a7);
        *(uint4*)&agg[nl * AP + il * 8] = o;
    }
    __syncthreads();

    // ---- MFMA: 8 waves x one 16-node tile; y overlays the wave's own agg rows --
    {
        int m = lane & 15, quad = lane >> 4;
        int nl = wid * 16 + m;
        int node = b * 128 + nl;
        bhalf8 Bc0 = *(const bhalf8*)&agg[nl * AP + quad * 8];
        bhalf8 Bc1 = *(const bhalf8*)&agg[nl * AP + 32 + quad * 8];
        unsigned short* ys = &agg[nl * AP];
#pragma unroll
        for (int tile = 0; tile < 4; tile++) {
            f32x4 a;
#pragma unroll
            for (int r = 0; r < 4; r++) a[r] = b1[tile * 16 + quad * 4 + r];
            bhalf8 A0 = *(const bhalf8*)&sW1t[(tile * 16 + m) * YP + quad * 8];
            bhalf8 A1 = *(const bhalf8*)&sW1t[(tile * 16 + m) * YP + 32 + quad * 8];
            a = __builtin_amdgcn_mfma_f32_16x16x32_bf16(A0, Bc0, a, 0, 0, 0);
            a = __builtin_amdgcn_mfma_f32_16x16x32_bf16(A1, Bc1, a, 0, 0, 0);
            float y0 = a[0] > 0.f ? a[0] : 0.f, y1 = a[1] > 0.f ? a[1] : 0.f;
            float y2 = a[2] > 0.f ? a[2] : 0.f, y3 = a[3] > 0.f ? a[3] : 0.f;
            uint2 o; o.x = pk2(y0, y1); o.y = pk2(y2, y3);
            *(uint2*)&ys[tile * 16 + quad * 4] = o;
        }
        __asm__ __volatile__("s_waitcnt lgkmcnt(0)" ::: "memory");
        union { bhalf8 v; uint2 u2[2]; } Y0, Y1;
        Y0.u2[0] = *(uint2*)&ys[quad * 8];
        Y0.u2[1] = *(uint2*)&ys[quad * 8 + 4];
        Y1.u2[0] = *(uint2*)&ys[32 + quad * 8];
        Y1.u2[1] = *(uint2*)&ys[32 + quad * 8 + 4];
#pragma unroll
        for (int tile = 0; tile < 2; tile++) {
            bhalf8 A0 = *(const bhalf8*)&sW2t[(tile * 16 + m) * YP + quad * 8];
            bhalf8 A1 = *(const bhalf8*)&sW2t[(tile * 16 + m) * YP + 32 + quad * 8];
            f32x4 z = {0.f, 0.f, 0.f, 0.f};
            z = __builtin_amdgcn_mfma_f32_16x16x32_bf16(A0, Y0.v, z, 0, 0, 0);
            z = __builtin_amdgcn_mfma_f32_16x16x32_bf16(A1, Y1.v, z, 0, 0, 0);
            if (node < N_NODES) {
                uint2 o; o.x = pk2(z[0], z[1]); o.y = pk2(z[2], z[3]);
                *(uint2*)&Zb[(size_t)node * 32 + tile * 16 + quad * 4] = o;
            }
        }
    }
}

// ---------------- bucket2: rank-sort + group-per-node gather of Zb + b2 --------
__global__ __launch_bounds__(512) void bucket2(
    const unsigned* __restrict__ ebuf, const int* __restrict__ gcur,
    const uint4* __restrict__ Zb4,
    const float* __restrict__ b2, float4* __restrict__ out4) {
    __shared__ int hh[128], nodeoff[129], scv[128];
    __shared__ int stg[CAP];
    int b = blockIdx.x, t = threadIdx.x;
    int base = b * CAP, cnt = gcur[b];
    int lane = t & 63, wid = t >> 6;
    if (t < 128) hh[t] = 0;
    __syncthreads();
    unsigned ev[6]; int ek = 0;
    for (int i = t; i < cnt; i += 512) {
        unsigned v = ebuf[base + i];
        ev[ek++] = v;
        atomicAdd(&hh[v & 127], 1);
    }
    __syncthreads();
    if (wid == 0) {
        int v0 = hh[2 * lane], v1 = hh[2 * lane + 1];
        int ps = v0 + v1, s = ps;
        for (int o = 1; o < 64; o <<= 1) {
            int u = __shfl_up(s, o);
            if (lane >= o) s += u;
        }
        int excl = s - ps;
        nodeoff[2 * lane] = excl;
        nodeoff[2 * lane + 1] = excl + v0;
    }
    __syncthreads();
    if (t < 128) scv[t] = nodeoff[t];
    __syncthreads();
    for (int k = 0; k < ek; k++) {
        unsigned v = ev[k];
        int r = atomicAdd(&scv[v & 127], 1);
        stg[r] = (int)(v >> 7);
    }
    __syncthreads();

    // ---- gather: 4-lane group owns one node (8 ch/lane), 4 rows in flight ----
    int il = lane & 3, g = lane >> 2;
    int nl = wid * 16 + g;
    int s0 = nodeoff[nl], d = hh[nl];
    float a0 = 0.f, a1 = 0.f, a2 = 0.f, a3 = 0.f;
    float a4 = 0.f, a5 = 0.f, a6 = 0.f, a7 = 0.f;
    int j = 0;
    for (; j + 3 < d; j += 4) {
        int sa = stg[s0 + j], sb = stg[s0 + j + 1];
        int sc = stg[s0 + j + 2], sd = stg[s0 + j + 3];
        uint4 va = Zb4[sa * 4 + il], vb = Zb4[sb * 4 + il];
        uint4 vc = Zb4[sc * 4 + il], vd = Zb4[sd * 4 + il];
        a0 += bl(va.x) + bl(vb.x) + bl(vc.x) + bl(vd.x);
        a1 += bh(va.x) + bh(vb.x) + bh(vc.x) + bh(vd.x);
        a2 += bl(va.y) + bl(vb.y) + bl(vc.y) + bl(vd.y);
        a3 += bh(va.y) + bh(vb.y) + bh(vc.y) + bh(vd.y);
        a4 += bl(va.z) + bl(vb.z) + bl(vc.z) + bl(vd.z);
        a5 += bh(va.z) + bh(vb.z) + bh(vc.z) + bh(vd.z);
        a6 += bl(va.w) + bl(vb.w) + bl(vc.w) + bl(vd.w);
        a7 += bh(va.w) + bh(vb.w) + bh(vc.w) + bh(vd.w);
    }
    for (; j < d; j++) {
        int sa = stg[s0 + j];
        uint4 va = Zb4[sa * 4 + il];
        a0 += bl(va.x); a1 += bh(va.x); a2 += bl(va.y); a3 += bh(va.y);
        a4 += bl(va.z); a5 += bh(va.z); a6 += bl(va.w); a7 += bh(va.w);
    }
    int node = b * 128 + nl;
    if (node < N_NODES) {
        float4 bbA = ((const float4*)b2)[il * 2];
        float4 bbB = ((const float4*)b2)[il * 2 + 1];
        float4 oA, oB;
        oA.x = a0 + bbA.x; oA.y = a1 + bbA.y; oA.z = a2 + bbA.z; oA.w = a3 + bbA.w;
        oB.x = a4 + bbB.x; oB.y = a5 + bbB.y; oB.z = a6 + bbB.z; oB.w = a7 + bbB.w;
        out4[node * 8 + il * 2] = oA;
        out4[node * 8 + il * 2 + 1] = oB;
    }
}

extern "C" void kernel_launch(void* const* d_in, const int* in_sizes, int n_in,
                              void* d_out, int out_size, void* d_ws, size_t ws_size,
                              hipStream_t stream) {
    const float* features = (const float*)d_in[0];
    const int*   src      = (const int*)d_in[1];
    const int*   dst      = (const int*)d_in[2];
    const float* W1       = (const float*)d_in[3];
    const float* b1       = (const float*)d_in[4];
    const float* W2       = (const float*)d_in[5];
    const float* b2       = (const float*)d_in[6];

    char* p = (char*)d_ws;
    int* gcur = (int*)p;           p += 1024 * 4;
    unsigned* ebuf = (unsigned*)p; p += (size_t)NB * CAP * 4;
    uint2* Xb = (uint2*)p;         p += (size_t)N_NODES * 64 * 2;
    unsigned short* Zb = (unsigned short*)p; p += (size_t)N_NODES * 32 * 2;

    hipMemsetAsync(gcur, 0, NB * sizeof(int), stream);
    prep<<<NP1 + CVB, 512, 0, stream>>>((const float4*)features, Xb, src, dst, gcur, ebuf);
    bucket1<<<NB, 512, 0, stream>>>(ebuf, gcur, (const uint4*)Xb, W1, b1, W2, Zb);
    bucket2<<<NB, 512, 0, stream>>>(ebuf, gcur, (const uint4*)Zb, b2, (float4*)d_out);
}

// Round 13
// 160.306 us; speedup vs baseline: 1.0489x; 1.0489x over previous
//
#include <hip/hip_runtime.h>

#define N_NODES 100000
#define N_EDGES 1600000
#define NB 782    // ceil(N_NODES/128) buckets of 128 dst-nodes
#define CAP 3072  // strip capacity per bucket (mean 2046, sigma 45 -> 22-sigma safe)
#define EPB 8192  // edges per pass1 block
#define NP1 196   // ceil(N_EDGES/EPB)
#define CVB 200   // convert blocks in prep
#define YP 72     // padded LDS row (bf16) for weights
#define AP 72     // padded LDS agg row (bf16)

typedef __attribute__((ext_vector_type(8))) short bhalf8;
typedef __attribute__((ext_vector_type(4))) float f32x4;

__device__ __forceinline__ unsigned short bf16r(float f) {
    unsigned u = __float_as_uint(f);
    unsigned r = (u >> 16) & 1;
    return (unsigned short)((u + 0x7fffu + r) >> 16);
}
__device__ __forceinline__ unsigned pk2(float a, float b) {
    return (unsigned)bf16r(a) | ((unsigned)bf16r(b) << 16);
}
__device__ __forceinline__ float bl(unsigned u) { return __uint_as_float(u << 16); }
__device__ __forceinline__ float bh(unsigned u) { return __uint_as_float(u & 0xffff0000u); }

// ---------------- prep: pass1 sort (blocks 0..NP1-1) || convert (rest) ---------
__global__ __launch_bounds__(512) void prep(const float4* __restrict__ X4,
                                            uint2* __restrict__ Xb,
                                            const int* __restrict__ src,
                                            const int* __restrict__ dst,
                                            int* __restrict__ gcur,
                                            unsigned* __restrict__ ebuf) {
    __shared__ int h[NB];                // hist, then gdelta
    __shared__ int lo[NB];
    __shared__ int cur[NB];
    __shared__ int wsum[8];
    __shared__ unsigned stage[EPB];      // 32 KB
    __shared__ unsigned short bid[EPB];  // 16 KB
    int t = threadIdx.x, lane = t & 63, wid = t >> 6;
    if (blockIdx.x >= NP1) {  // convert branch
        for (int i = (blockIdx.x - NP1) * 512 + t; i < N_NODES * 16; i += CVB * 512) {
            float4 v = X4[i];
            uint2 o; o.x = pk2(v.x, v.y); o.y = pk2(v.z, v.w);
            Xb[i] = o;
        }
        return;
    }
    int e0 = blockIdx.x * EPB;
    int eN = N_EDGES - e0; if (eN > EPB) eN = EPB;
    for (int b = t; b < NB; b += 512) h[b] = 0;
    __syncthreads();
    for (int i = t; i < eN; i += 512) atomicAdd(&h[dst[e0 + i] >> 7], 1);
    __syncthreads();
    int i0 = 2 * t, i1 = i0 + 1;
    int v0 = (i0 < NB) ? h[i0] : 0;
    int v1 = (i1 < NB) ? h[i1] : 0;
    int ps = v0 + v1, s = ps;
    for (int o = 1; o < 64; o <<= 1) {
        int u = __shfl_up(s, o);
        if (lane >= o) s += u;
    }
    if (lane == 63) wsum[wid] = s;
    __syncthreads();
    int wofs = 0;
    for (int w = 0; w < wid; w++) wofs += wsum[w];
    int excl = wofs + s - ps;
    if (i0 < NB) lo[i0] = excl;
    if (i1 < NB) lo[i1] = excl + v0;
    __syncthreads();
    for (int b = t; b < NB; b += 512) {
        int hb = h[b];
        int ofs = hb ? atomicAdd(&gcur[b], hb) : 0;
        h[b] = b * CAP + ofs - lo[b];
        cur[b] = lo[b];
    }
    __syncthreads();
    for (int i = t; i < eN; i += 512) {
        int sd = src[e0 + i], dd = dst[e0 + i];
        int b = dd >> 7;
        int r = atomicAdd(&cur[b], 1);
        stage[r] = ((unsigned)sd << 7) | (unsigned)(dd & 127);
        bid[r] = (unsigned short)b;
    }
    __syncthreads();
    for (int i = t; i < eN; i += 512)
        ebuf[h[bid[i]] + i] = stage[i];
}

// ---------------- bucket1: rank-sort + group-per-node gather + MFMA gemm -------
// LDS time-multiplex: pool holds stg (sort+gather phases), then W1^T/W2^T
// (MFMA phase). 33.4 KB total -> 4 blocks/CU (wave cap), all 782 co-resident.
__global__ __launch_bounds__(512) void bucket1(
    const unsigned* __restrict__ ebuf, const int* __restrict__ gcur,
    const uint4* __restrict__ Xb4,
    const float* __restrict__ W1, const float* __restrict__ b1,
    const float* __restrict__ W2,
    unsigned short* __restrict__ Zb) {
    __shared__ int hh[128], nodeoff[129], scv[128];
    __shared__ unsigned short agg[128 * AP];   // 18432 B agg tile [nl][ch] (bf16)
    __shared__ int pool[3456];                 // 13824 B: stg (12288) / weights
    int* stg = pool;
    unsigned short* sW1t = (unsigned short*)pool;           // 9216 B  W1^T [h][k]
    unsigned short* sW2t = (unsigned short*)(pool + 2304);  // 4608 B  W2^T [oc][h]

    int b = blockIdx.x, t = threadIdx.x;
    int base = b * CAP, cnt = gcur[b];
    int lane = t & 63, wid = t >> 6;
    if (t < 128) hh[t] = 0;
    __syncthreads();
    unsigned ev[6]; int ek = 0;
    for (int i = t; i < cnt; i += 512) {
        unsigned v = ebuf[base + i];
        ev[ek++] = v;
        atomicAdd(&hh[v & 127], 1);
    }
    __syncthreads();
    if (wid == 0) {  // wave-parallel exclusive scan of 128 (2 elems/lane)
        int v0 = hh[2 * lane], v1 = hh[2 * lane + 1];
        int ps = v0 + v1, s = ps;
        for (int o = 1; o < 64; o <<= 1) {
            int u = __shfl_up(s, o);
            if (lane >= o) s += u;
        }
        int excl = s - ps;
        nodeoff[2 * lane] = excl;
        nodeoff[2 * lane + 1] = excl + v0;
    }
    __syncthreads();
    if (t < 128) scv[t] = nodeoff[t];
    __syncthreads();
    for (int k = 0; k < ek; k++) {
        unsigned v = ev[k];
        int r = atomicAdd(&scv[v & 127], 1);
        stg[r] = (int)(v >> 7);
    }
    __syncthreads();

    // ---- gather: 8-lane group owns one node (8 ch/lane), 4 rows in flight ----
    int il = lane & 7, g = lane >> 3;
#pragma unroll
    for (int half = 0; half < 2; half++) {
        int nl = wid * 16 + half * 8 + g;
        int s0 = nodeoff[nl], d = hh[nl];
        float a0 = 0.f, a1 = 0.f, a2 = 0.f, a3 = 0.f;
        float a4 = 0.f, a5 = 0.f, a6 = 0.f, a7 = 0.f;
        int j = 0;
        for (; j + 3 < d; j += 4) {
            int sa = stg[s0 + j], sb = stg[s0 + j + 1];
            int sc = stg[s0 + j + 2], sd = stg[s0 + j + 3];
            uint4 va = Xb4[sa * 8 + il], vb = Xb4[sb * 8 + il];
            uint4 vc = Xb4[sc * 8 + il], vd = Xb4[sd * 8 + il];
            a0 += bl(va.x) + bl(vb.x) + bl(vc.x) + bl(vd.x);
            a1 += bh(va.x) + bh(vb.x) + bh(vc.x) + bh(vd.x);
            a2 += bl(va.y) + bl(vb.y) + bl(vc.y) + bl(vd.y);
            a3 += bh(va.y) + bh(vb.y) + bh(vc.y) + bh(vd.y);
            a4 += bl(va.z) + bl(vb.z) + bl(vc.z) + bl(vd.z);
            a5 += bh(va.z) + bh(vb.z) + bh(vc.z) + bh(vd.z);
            a6 += bl(va.w) + bl(vb.w) + bl(vc.w) + bl(vd.w);
            a7 += bh(va.w) + bh(vb.w) + bh(vc.w) + bh(vd.w);
        }
        for (; j < d; j++) {
            int sa = stg[s0 + j];
            uint4 va = Xb4[sa * 8 + il];
            a0 += bl(va.x); a1 += bh(va.x); a2 += bl(va.y); a3 += bh(va.y);
            a4 += bl(va.z); a5 += bh(va.z); a6 += bl(va.w); a7 += bh(va.w);
        }
        uint4 o;
        o.x = pk2(a0, a1); o.y = pk2(a2, a3);
        o.z = pk2(a4, a5); o.w = pk2(a6, a7);
        *(uint4*)&agg[nl * AP + il * 8] = o;
    }
    __syncthreads();

    // ---- stg is dead: load weights into the pool ----
    for (int i = t; i < 64 * 64; i += 512) {
        int k = i >> 6, hc = i & 63;
        sW1t[hc * YP + k] = bf16r(W1[k * 64 + hc]);
    }
    for (int i = t; i < 64 * 32; i += 512) {
        int k = i >> 5, oc = i & 31;
        sW2t[oc * YP + k] = bf16r(W2[k * 32 + oc]);
    }
    __syncthreads();

    // ---- MFMA: 8 waves x one 16-node tile; y overlays the wave's own agg rows --
    {
        int m = lane & 15, quad = lane >> 4;
        int nl = wid * 16 + m;
        int node = b * 128 + nl;
        bhalf8 Bc0 = *(const bhalf8*)&agg[nl * AP + quad * 8];
        bhalf8 Bc1 = *(const bhalf8*)&agg[nl * AP + 32 + quad * 8];
        unsigned short* ys = &agg[nl * AP];
#pragma unroll
        for (int tile = 0; tile < 4; tile++) {
            f32x4 a;
#pragma unroll
            for (int r = 0; r < 4; r++) a[r] = b1[tile * 16 + quad * 4 + r];
            bhalf8 A0 = *(const bhalf8*)&sW1t[(tile * 16 + m) * YP + quad * 8];
            bhalf8 A1 = *(const bhalf8*)&sW1t[(tile * 16 + m) * YP + 32 + quad * 8];
            a = __builtin_amdgcn_mfma_f32_16x16x32_bf16(A0, Bc0, a, 0, 0, 0);
            a = __builtin_amdgcn_mfma_f32_16x16x32_bf16(A1, Bc1, a, 0, 0, 0);
            float y0 = a[0] > 0.f ? a[0] : 0.f, y1 = a[1] > 0.f ? a[1] : 0.f;
            float y2 = a[2] > 0.f ? a[2] : 0.f, y3 = a[3] > 0.f ? a[3] : 0.f;
            uint2 o; o.x = pk2(y0, y1); o.y = pk2(y2, y3);
            *(uint2*)&ys[tile * 16 + quad * 4] = o;
        }
        __asm__ __volatile__("s_waitcnt lgkmcnt(0)" ::: "memory");
        union { bhalf8 v; uint2 u2[2]; } Y0, Y1;
        Y0.u2[0] = *(uint2*)&ys[quad * 8];
        Y0.u2[1] = *(uint2*)&ys[quad * 8 + 4];
        Y1.u2[0] = *(uint2*)&ys[32 + quad * 8];
        Y1.u2[1] = *(uint2*)&ys[32 + quad * 8 + 4];
#pragma unroll
        for (int tile = 0; tile < 2; tile++) {
            bhalf8 A0 = *(const bhalf8*)&sW2t[(tile * 16 + m) * YP + quad * 8];
            bhalf8 A1 = *(const bhalf8*)&sW2t[(tile * 16 + m) * YP + 32 + quad * 8];
            f32x4 z = {0.f, 0.f, 0.f, 0.f};
            z = __builtin_amdgcn_mfma_f32_16x16x32_bf16(A0, Y0.v, z, 0, 0, 0);
            z = __builtin_amdgcn_mfma_f32_16x16x32_bf16(A1, Y1.v, z, 0, 0, 0);
            if (node < N_NODES) {
                uint2 o; o.x = pk2(z[0], z[1]); o.y = pk2(z[2], z[3]);
                *(uint2*)&Zb[(size_t)node * 32 + tile * 16 + quad * 4] = o;
            }
        }
    }
}

// ---------------- bucket2: rank-sort + group-per-node gather of Zb + b2 --------
__global__ __launch_bounds__(512) void bucket2(
    const unsigned* __restrict__ ebuf, const int* __restrict__ gcur,
    const uint4* __restrict__ Zb4,
    const float* __restrict__ b2, float4* __restrict__ out4) {
    __shared__ int hh[128], nodeoff[129], scv[128];
    __shared__ int stg[CAP];
    int b = blockIdx.x, t = threadIdx.x;
    int base = b * CAP, cnt = gcur[b];
    int lane = t & 63, wid = t >> 6;
    if (t < 128) hh[t] = 0;
    __syncthreads();
    unsigned ev[6]; int ek = 0;
    for (int i = t; i < cnt; i += 512) {
        unsigned v = ebuf[base + i];
        ev[ek++] = v;
        atomicAdd(&hh[v & 127], 1);
    }
    __syncthreads();
    if (wid == 0) {
        int v0 = hh[2 * lane], v1 = hh[2 * lane + 1];
        int ps = v0 + v1, s = ps;
        for (int o = 1; o < 64; o <<= 1) {
            int u = __shfl_up(s, o);
            if (lane >= o) s += u;
        }
        int excl = s - ps;
        nodeoff[2 * lane] = excl;
        nodeoff[2 * lane + 1] = excl + v0;
    }
    __syncthreads();
    if (t < 128) scv[t] = nodeoff[t];
    __syncthreads();
    for (int k = 0; k < ek; k++) {
        unsigned v = ev[k];
        int r = atomicAdd(&scv[v & 127], 1);
        stg[r] = (int)(v >> 7);
    }
    __syncthreads();

    // ---- gather: 4-lane group owns one node (8 ch/lane), 4 rows in flight ----
    int il = lane & 3, g = lane >> 2;
    int nl = wid * 16 + g;
    int s0 = nodeoff[nl], d = hh[nl];
    float a0 = 0.f, a1 = 0.f, a2 = 0.f, a3 = 0.f;
    float a4 = 0.f, a5 = 0.f, a6 = 0.f, a7 = 0.f;
    int j = 0;
    for (; j + 3 < d; j += 4) {
        int sa = stg[s0 + j], sb = stg[s0 + j + 1];
        int sc = stg[s0 + j + 2], sd = stg[s0 + j + 3];
        uint4 va = Zb4[sa * 4 + il], vb = Zb4[sb * 4 + il];
        uint4 vc = Zb4[sc * 4 + il], vd = Zb4[sd * 4 + il];
        a0 += bl(va.x) + bl(vb.x) + bl(vc.x) + bl(vd.x);
        a1 += bh(va.x) + bh(vb.x) + bh(vc.x) + bh(vd.x);
        a2 += bl(va.y) + bl(vb.y) + bl(vc.y) + bl(vd.y);
        a3 += bh(va.y) + bh(vb.y) + bh(vc.y) + bh(vd.y);
        a4 += bl(va.z) + bl(vb.z) + bl(vc.z) + bl(vd.z);
        a5 += bh(va.z) + bh(vb.z) + bh(vc.z) + bh(vd.z);
        a6 += bl(va.w) + bl(vb.w) + bl(vc.w) + bl(vd.w);
        a7 += bh(va.w) + bh(vb.w) + bh(vc.w) + bh(vd.w);
    }
    for (; j < d; j++) {
        int sa = stg[s0 + j];
        uint4 va = Zb4[sa * 4 + il];
        a0 += bl(va.x); a1 += bh(va.x); a2 += bl(va.y); a3 += bh(va.y);
        a4 += bl(va.z); a5 += bh(va.z); a6 += bl(va.w); a7 += bh(va.w);
    }
    int node = b * 128 + nl;
    if (node < N_NODES) {
        float4 bbA = ((const float4*)b2)[il * 2];
        float4 bbB = ((const float4*)b2)[il * 2 + 1];
        float4 oA, oB;
        oA.x = a0 + bbA.x; oA.y = a1 + bbA.y; oA.z = a2 + bbA.z; oA.w = a3 + bbA.w;
        oB.x = a4 + bbB.x; oB.y = a5 + bbB.y; oB.z = a6 + bbB.z; oB.w = a7 + bbB.w;
        out4[node * 8 + il * 2] = oA;
        out4[node * 8 + il * 2 + 1] = oB;
    }
}

extern "C" void kernel_launch(void* const* d_in, const int* in_sizes, int n_in,
                              void* d_out, int out_size, void* d_ws, size_t ws_size,
                              hipStream_t stream) {
    const float* features = (const float*)d_in[0];
    const int*   src      = (const int*)d_in[1];
    const int*   dst      = (const int*)d_in[2];
    const float* W1       = (const float*)d_in[3];
    const float* b1       = (const float*)d_in[4];
    const float* W2       = (const float*)d_in[5];
    const float* b2       = (const float*)d_in[6];

    char* p = (char*)d_ws;
    int* gcur = (int*)p;           p += 1024 * 4;
    unsigned* ebuf = (unsigned*)p; p += (size_t)NB * CAP * 4;
    uint2* Xb = (uint2*)p;         p += (size_t)N_NODES * 64 * 2;
    unsigned short* Zb = (unsigned short*)p; p += (size_t)N_NODES * 32 * 2;

    hipMemsetAsync(gcur, 0, NB * sizeof(int), stream);
    prep<<<NP1 + CVB, 512, 0, stream>>>((const float4*)features, Xb, src, dst, gcur, ebuf);
    bucket1<<<NB, 512, 0, stream>>>(ebuf, gcur, (const uint4*)Xb, W1, b1, W2, Zb);
    bucket2<<<NB, 512, 0, stream>>>(ebuf, gcur, (const uint4*)Zb, b2, (float4*)d_out);
}